// Round 7
// baseline (67.036 us; speedup 1.0000x reference)
//
#include <hip/hip_runtime.h>

#define LEAK 0.01f

typedef float v2f __attribute__((ext_vector_type(2)));
typedef _Float16 h2 __attribute__((ext_vector_type(2)));

// Problem constants
constexpr int H = 1024, W = 1024, NIMG = 4;
constexpr int GC = 12, GD = 12, GH = 16, GW = 16;
constexpr int NZ = GD - 1;           // 11 z0 values (z-pairs)
constexpr int CELLE = NZ * GC;       // 132 half2 per (y,x) grid cell
constexpr int CF4 = 33;              // float4 chunks per cell (132 h2 = 528 B)

// Tiling: 256 threads (64x4), each thread does 4 pixels along x -> 256x4 tile
constexpr int PX = 4;
constexpr int BX = 64, BY = 4;
constexpr int TILE_W = BX * PX;      // 256
constexpr int XS = 6;                // x-cell footprint of a 256-wide tile

static __device__ __forceinline__ h2 bch2(float f) {
    return __builtin_bit_cast(h2, f);
}
static __device__ __forceinline__ float bcf(h2 v) {
    return __builtin_bit_cast(float, v);
}
// cvt_pkrtz returns __fp16x2; bit-cast to our h2 (_Float16x2) — same bits.
static __device__ __forceinline__ h2 pkrtz(float a, float b) {
    return __builtin_bit_cast(h2, __builtin_amdgcn_cvt_pkrtz(a, b));
}

static __device__ __forceinline__ float fdot2f(h2 a, h2 b, float c) {
#if __has_builtin(__builtin_amdgcn_fdot2)
    return __builtin_amdgcn_fdot2(a, b, c, false);
#else
    return (float)a.x * (float)b.x + (float)a.y * (float)b.y + c;
#endif
}

// ---- pre-kernel: build z-pair half2 table in ws ----
// table layout: [n][y*16+x][z0*12+c]  (132 half2 = 528 B contiguous per cell)
__global__ __launch_bounds__(256) void pairgen(const float* __restrict__ grid,
                                               h2* __restrict__ table) {
    const int n  = blockIdx.x / NZ;
    const int z0 = blockIdx.x % NZ;
    const int yx = threadIdx.x;      // 0..255, coalesced over lanes
    const float* src = grid + (size_t)n * GC * GD * GH * GW + yx;
    h2* dst = table + ((size_t)n * 256 + yx) * CELLE + z0 * GC;
    #pragma unroll
    for (int c = 0; c < GC; ++c) {
        float a = src[(c * GD + z0) * 256];
        float b = src[(c * GD + z0 + 1) * 256];
        dst[c] = pkrtz(a, b);
    }
}

// ================= Kernel G: conv + guide (streaming, no LDS) =================
// Writes clipped guide (fp32) into out[n][0] plane (overwritten later by S).
__global__ __launch_bounds__(256) void guide_conv(
    const float* __restrict__ full,   // (N,3,H,W)
    const float* __restrict__ w1,     // (3,3,1,1)
    const float* __restrict__ w3,     // (3,3,3,3)
    const float* __restrict__ b3,     // (3)
    const float* __restrict__ bias,   // (1)
    float* __restrict__ out)          // guide -> out + n*3*plane
{
    const int n  = blockIdx.z;
    const int h  = blockIdx.y * BY + threadIdx.y;
    const int w0 = blockIdx.x * TILE_W + threadIdx.x * PX;
    const size_t plane = (size_t)H * W;
    const float* fn = full + (size_t)n * 3 * plane;

    float w1c[3][3];
    #pragma unroll
    for (int o = 0; o < 3; ++o)
        #pragma unroll
        for (int i = 0; i < 3; ++i)
            w1c[o][i] = w1[o * 3 + i];
    const float biasv = bias[0];

    v2f a3p[3][2];
    #pragma unroll
    for (int o = 0; o < 3; ++o) {
        float b = b3[o];
        a3p[o][0] = (v2f){b, b};
        a3p[o][1] = (v2f){b, b};
    }
    float rgb[3][PX];

    const bool xfast = (w0 >= 4) && (w0 <= W - 12);

    #pragma unroll
    for (int i = 0; i < 3; ++i) {
        const float* fc = fn + (size_t)i * plane;
        #pragma unroll
        for (int dy = 0; dy < 3; ++dy) {
            int yy = h + dy - 1;
            float row[8];   // positions w0-1 .. w0+6
            if (yy >= 0 && yy < H) {
                const float* rp = fc + (size_t)yy * W;
                if (xfast) {
                    const float4* q = (const float4*)(rp + w0 - 4);
                    float4 v0 = q[0], v1 = q[1], v2 = q[2];
                    row[0] = v0.w;
                    row[1] = v1.x; row[2] = v1.y; row[3] = v1.z; row[4] = v1.w;
                    row[5] = v2.x; row[6] = v2.y; row[7] = v2.z;
                } else {
                    #pragma unroll
                    for (int k = 0; k < 8; ++k) {
                        int xx = w0 - 1 + k;
                        row[k] = (xx >= 0 && xx < W) ? rp[xx] : 0.0f;
                    }
                }
            } else {
                #pragma unroll
                for (int k = 0; k < 8; ++k) row[k] = 0.0f;
            }
            if (dy == 1) {
                #pragma unroll
                for (int j = 0; j < PX; ++j) rgb[i][j] = row[1 + j];
            }
            #pragma unroll
            for (int o = 0; o < 3; ++o) {
                const float* kp = w3 + ((o * 3 + i) * 3 + dy) * 3;
                #pragma unroll
                for (int t = 0; t < 3; ++t) {
                    const float kt = kp[t];
                    v2f kv = (v2f){kt, kt};
                    a3p[o][0] = __builtin_elementwise_fma(
                        kv, (v2f){row[t], row[t + 1]}, a3p[o][0]);
                    a3p[o][1] = __builtin_elementwise_fma(
                        kv, (v2f){row[t + 2], row[t + 3]}, a3p[o][1]);
                }
            }
        }
    }

    float4 gv;
    float* gvp = &gv.x;
    #pragma unroll
    for (int j = 0; j < PX; ++j) {
        float gacc = 0.0f;
        #pragma unroll
        for (int o = 0; o < 3; ++o) {
            float x1 = fmaf(w1c[o][0], rgb[0][j],
                       fmaf(w1c[o][1], rgb[1][j], w1c[o][2] * rgb[2][j]));
            x1 = (x1 > 0.0f) ? x1 : LEAK * x1;
            float x3 = a3p[o][j >> 1][j & 1];
            x3 = (x3 > 0.0f) ? x3 : LEAK * x3;
            gacc += x1 + x3;
        }
        float g = fmaf(gacc, (1.0f / 3.0f), biasv);
        gvp[j] = fminf(fmaxf(g, 0.0f), 1.0f);
    }

    *(float4*)(out + (size_t)n * 3 * plane + (size_t)h * W + w0) = gv;
}

// ================= Kernel S: slice + apply =================
// Reads guide from out[n][0] (written by G), overwrites all 3 out channels.
// NOTE: out is NOT __restrict__ (guide aliases the channel-0 stores).
__global__ __launch_bounds__(256) void slice_apply(
    const float* __restrict__ grid,   // (N,12,12,16,16)
    const float* __restrict__ full,   // (N,3,H,W)
    const h2* __restrict__ table,     // pair table or nullptr
    float* out)                       // (N,3,H,W); ch0 holds guide on entry
{
    // y-LERPED z-pair slab: [thread-row][x-cell][z0*12+c]
    __shared__ __align__(16) h2 sgrid[BY * XS * CELLE];

    const int n  = blockIdx.z;
    const int wb = blockIdx.x * TILE_W;
    const int hb = blockIdx.y * BY;

    const float scale = 15.0f / 1023.0f;
    const int xlo = (int)(wb * scale);

    const int h  = hb + threadIdx.y;
    const int w0 = wb + threadIdx.x * PX;
    const size_t plane = (size_t)H * W;
    const float* fn = full + (size_t)n * 3 * plane;
    float* ob = out + (size_t)n * 3 * plane + (size_t)h * W + w0;

    // ---- issue independent global loads EARLY (hide under staging) ----
    float4 gv = *(const float4*)(ob);            // guide for 4 px (ch0 plane)
    float4 rv0 = *(const float4*)(fn + (size_t)h * W + w0);
    float4 rv1 = *(const float4*)(fn + plane + (size_t)h * W + w0);
    float4 rv2 = *(const float4*)(fn + 2 * plane + (size_t)h * W + w0);

    const int tid = threadIdx.y * BX + threadIdx.x;

    // ---- stage y-interpolated z-pair slab into LDS ----
    if (table) {
        const float4* tsrc = (const float4*)(table + (size_t)n * 256 * CELLE);
        float4* sdst = (float4*)sgrid;
        for (int e = tid; e < BY * XS * CF4; e += BX * BY) {   // 792 items
            int r  = e / (XS * CF4);
            int t  = e - r * (XS * CF4);
            int lx = t / CF4, q = t - lx * CF4;
            int yy = hb + r;
            float fy = (float)yy * scale;
            int y0 = min((int)fy, GH - 2);
            float ty = fy - (float)y0;
            _Float16 t1 = (_Float16)ty, t0 = (_Float16)(1.0f - ty);
            h2 w0v = (h2){t0, t0}, w1v = (h2){t1, t1};
            int xi = min(xlo + lx, GW - 1);
            const float4* pa = tsrc + (y0 * GW + xi) * CF4 + q;
            const float4* pb = tsrc + ((y0 + 1) * GW + xi) * CF4 + q;
            float4 A = *pa, B = *pb, R;
            R.x = bcf(bch2(A.x) * w0v + bch2(B.x) * w1v);
            R.y = bcf(bch2(A.y) * w0v + bch2(B.y) * w1v);
            R.z = bcf(bch2(A.z) * w0v + bch2(B.z) * w1v);
            R.w = bcf(bch2(A.w) * w0v + bch2(B.w) * w1v);
            sdst[e] = R;
        }
    } else {
        const float* gnn = grid + (size_t)n * GC * GD * GH * GW;
        for (int e = tid; e < BY * XS * CELLE; e += BX * BY) {
            int r  = e / (XS * CELLE);
            int t  = e - r * (XS * CELLE);
            int lx = t / CELLE, u = t - lx * CELLE;
            int z0 = u / GC, c = u - z0 * GC;
            int yy = hb + r;
            float fy = (float)yy * scale;
            int y0 = min((int)fy, GH - 2);
            float ty = fy - (float)y0;
            int xi = min(xlo + lx, GW - 1);
            const float* gp = gnn + ((c * GD + z0) * GH + y0) * GW + xi;
            float a0 = gp[0],  a1 = gp[256];        // z0 / z0+1 at y0
            float b0 = gp[16], b1 = gp[272];        // z0 / z0+1 at y0+1
            sgrid[e] = pkrtz(fmaf(b0 - a0, ty, a0), fmaf(b1 - a1, ty, a1));
        }
    }
    __syncthreads();

    const int srow = threadIdx.y * XS;       // this thread-row's cell base
    const float4* sg4 = (const float4*)sgrid;

    const float* gvp = &gv.x;
    const float* rp0 = &rv0.x;
    const float* rp1 = &rv1.x;
    const float* rp2 = &rv2.x;

    float4 ov0, ov1, ov2;
    float* ov0p = &ov0.x; float* ov1p = &ov1.x; float* ov2p = &ov2.x;

    #pragma unroll
    for (int j = 0; j < PX; ++j) {
        const float g = gvp[j];              // already clipped by G

        // slice coords (y already folded into LDS)
        float fx = (float)(w0 + j) * scale;
        int x0 = (int)fx;
        x0 = min(x0, GW - 2);
        float tx = fx - (float)x0;
        const int lxr = x0 - xlo;      // 0..4

        float fz = g * 11.0f;
        int z0 = (int)fz;
        z0 = min(z0, GD - 2);
        float tz = fz - (float)z0;
        h2 hz = pkrtz(1.0f - tz, tz);
        _Float16 hx0 = (_Float16)(1.0f - tx), hx1 = (_Float16)tx;
        h2 wA = hz * (h2){hx0, hx0};   // v_pk_mul_f16
        h2 wB = hz * (h2){hx1, hx1};

        const float4* pA = sg4 + (srow + lxr) * CF4 + z0 * 3;
        const float4* pB = pA + CF4;
        float4 A0 = pA[0], A1 = pA[1], A2 = pA[2];
        float4 B0 = pB[0], B1 = pB[1], B2 = pB[2];

        float co[12];
        co[0]  = fdot2f(wA, bch2(A0.x), fdot2f(wB, bch2(B0.x), 0.0f));
        co[1]  = fdot2f(wA, bch2(A0.y), fdot2f(wB, bch2(B0.y), 0.0f));
        co[2]  = fdot2f(wA, bch2(A0.z), fdot2f(wB, bch2(B0.z), 0.0f));
        co[3]  = fdot2f(wA, bch2(A0.w), fdot2f(wB, bch2(B0.w), 0.0f));
        co[4]  = fdot2f(wA, bch2(A1.x), fdot2f(wB, bch2(B1.x), 0.0f));
        co[5]  = fdot2f(wA, bch2(A1.y), fdot2f(wB, bch2(B1.y), 0.0f));
        co[6]  = fdot2f(wA, bch2(A1.z), fdot2f(wB, bch2(B1.z), 0.0f));
        co[7]  = fdot2f(wA, bch2(A1.w), fdot2f(wB, bch2(B1.w), 0.0f));
        co[8]  = fdot2f(wA, bch2(A2.x), fdot2f(wB, bch2(B2.x), 0.0f));
        co[9]  = fdot2f(wA, bch2(A2.y), fdot2f(wB, bch2(B2.y), 0.0f));
        co[10] = fdot2f(wA, bch2(A2.z), fdot2f(wB, bch2(B2.z), 0.0f));
        co[11] = fdot2f(wA, bch2(A2.w), fdot2f(wB, bch2(B2.w), 0.0f));

        // apply
        const float r = rp0[j], gg = rp1[j], b = rp2[j];
        ov0p[j] = fmaf(co[0], r, fmaf(co[1],  gg, fmaf(co[2],  b, co[3])));
        ov1p[j] = fmaf(co[4], r, fmaf(co[5],  gg, fmaf(co[6],  b, co[7])));
        ov2p[j] = fmaf(co[8], r, fmaf(co[9],  gg, fmaf(co[10], b, co[11])));
    }

    // ---- coalesced float4 stores ----
    *(float4*)(ob)             = ov0;
    *(float4*)(ob + plane)     = ov1;
    *(float4*)(ob + 2 * plane) = ov2;
}

extern "C" void kernel_launch(void* const* d_in, const int* in_sizes, int n_in,
                              void* d_out, int out_size, void* d_ws, size_t ws_size,
                              hipStream_t stream) {
    const float* grid_p = (const float*)d_in[0];
    const float* full_p = (const float*)d_in[1];
    const float* w1_p   = (const float*)d_in[2];
    const float* w3_p   = (const float*)d_in[3];
    const float* b3_p   = (const float*)d_in[4];
    const float* bias_p = (const float*)d_in[5];
    float* out_p = (float*)d_out;

    const size_t tbytes = (size_t)NIMG * 256 * CELLE * sizeof(h2);  // 540,672 B
    h2* table = (d_ws && ws_size >= tbytes) ? (h2*)d_ws : nullptr;

    if (table) {
        hipLaunchKernelGGL(pairgen, dim3(NIMG * NZ), dim3(256), 0, stream,
                           grid_p, table);
    }

    dim3 block(BX, BY, 1);
    dim3 grid_dim(W / TILE_W, H / BY, NIMG);
    hipLaunchKernelGGL(guide_conv, grid_dim, block, 0, stream,
                       full_p, w1_p, w3_p, b3_p, bias_p, out_p);
    hipLaunchKernelGGL(slice_apply, grid_dim, block, 0, stream,
                       grid_p, full_p, table, out_p);
}

// Round 8
// 46.289 us; speedup vs baseline: 1.4482x; 1.4482x over previous
//
#include <hip/hip_runtime.h>

#define LEAK 0.01f

typedef float v2f __attribute__((ext_vector_type(2)));
typedef _Float16 h2 __attribute__((ext_vector_type(2)));

// Problem constants
constexpr int H = 1024, W = 1024, NIMG = 4;
constexpr int GC = 12, GD = 12, GH = 16, GW = 16;
constexpr int NZ = GD - 1;           // 11 z0 values (z-pairs)
constexpr int CELLE = NZ * GC;       // 132 half2 per (y,x) grid cell
constexpr int CF4 = 33;              // float4 chunks per cell (132 h2 = 528 B)

// Tiling: 256 threads (64x4), each thread does 4 pixels along x -> 256x4 tile
constexpr int PX = 4;
constexpr int BX = 64, BY = 4;
constexpr int TILE_W = BX * PX;      // 256
constexpr int XS = 6;                // x-cell footprint of a 256-wide tile

// fullres LDS slab: origin at global x = wb-4 (16B-aligned both sides)
constexpr int IMROWS = BY + 2;       // 6 rows: hb-1 .. hb+4
constexpr int IMW    = 268;          // covers [wb-4, wb+264)
constexpr int IMC4   = IMW / 4;      // 67 float4 chunks per row
constexpr int IMCH   = IMROWS * IMW; // floats per channel

static __device__ __forceinline__ h2 bch2(float f) {
    return __builtin_bit_cast(h2, f);
}
static __device__ __forceinline__ float bcf(h2 v) {
    return __builtin_bit_cast(float, v);
}
// cvt_pkrtz returns __fp16x2; bit-cast to our h2 (_Float16x2) — same bits.
static __device__ __forceinline__ h2 pkrtz(float a, float b) {
    return __builtin_bit_cast(h2, __builtin_amdgcn_cvt_pkrtz(a, b));
}

static __device__ __forceinline__ float fdot2f(h2 a, h2 b, float c) {
#if __has_builtin(__builtin_amdgcn_fdot2)
    return __builtin_amdgcn_fdot2(a, b, c, false);
#else
    return (float)a.x * (float)b.x + (float)a.y * (float)b.y + c;
#endif
}

// ---- pre-kernel: build z-pair half2 table in ws ----
// table layout: [n][y*16+x][z0*12+c]  (132 half2 = 528 B contiguous per cell)
__global__ __launch_bounds__(256) void pairgen(const float* __restrict__ grid,
                                               h2* __restrict__ table) {
    const int n  = blockIdx.x / NZ;
    const int z0 = blockIdx.x % NZ;
    const int yx = threadIdx.x;      // 0..255, coalesced over lanes
    const float* src = grid + (size_t)n * GC * GD * GH * GW + yx;
    h2* dst = table + ((size_t)n * 256 + yx) * CELLE + z0 * GC;
    #pragma unroll
    for (int c = 0; c < GC; ++c) {
        float a = src[(c * GD + z0) * 256];
        float b = src[(c * GD + z0 + 1) * 256];
        dst[c] = pkrtz(a, b);
    }
}

__global__ __launch_bounds__(256) void hdrnet_fused(
    const float* __restrict__ grid,   // (N,12,12,16,16)
    const float* __restrict__ full,   // (N,3,H,W)
    const float* __restrict__ w1,     // (3,3,1,1)
    const float* __restrict__ w3,     // (3,3,3,3)
    const float* __restrict__ b3,     // (3)
    const float* __restrict__ bias,   // (1)
    const h2* __restrict__ table,     // pair table or nullptr
    float* __restrict__ out)          // (N,3,H,W)
{
    __shared__ __align__(16) float simg[3 * IMCH];       // 19296 B
    __shared__ __align__(16) h2 sgrid[BY * XS * CELLE];  // 12672 B

    const int n  = blockIdx.z;
    const int wb = blockIdx.x * TILE_W;
    const int hb = blockIdx.y * BY;

    const float scale = 15.0f / 1023.0f;
    const int xlo = (int)(wb * scale);

    const int tid = threadIdx.y * BX + threadIdx.x;
    const size_t plane = (size_t)H * W;
    const float* fn = full + (size_t)n * 3 * plane;

    // ---- stage fullres tile into LDS (coalesced, zero-padded SAME) ----
    for (int e = tid; e < 3 * IMROWS * IMC4; e += BX * BY) {   // 1206 chunks
        int ch = e / (IMROWS * IMC4);
        int t  = e - ch * (IMROWS * IMC4);
        int r  = t / IMC4, m = t - r * IMC4;
        int yy = hb + r - 1;
        int gx = wb - 4 + 4 * m;
        float4 v = (float4){0.0f, 0.0f, 0.0f, 0.0f};
        if ((unsigned)yy < (unsigned)H && (unsigned)gx < (unsigned)W)
            v = *(const float4*)(fn + (size_t)ch * plane + (size_t)yy * W + gx);
        *(float4*)&simg[ch * IMCH + r * IMW + 4 * m] = v;
    }

    // ---- stage y-interpolated z-pair slab into LDS ----
    if (table) {
        const float4* tsrc = (const float4*)(table + (size_t)n * 256 * CELLE);
        float4* sdst = (float4*)sgrid;
        for (int e = tid; e < BY * XS * CF4; e += BX * BY) {   // 792 items
            int r  = e / (XS * CF4);
            int t  = e - r * (XS * CF4);
            int lx = t / CF4, q = t - lx * CF4;
            int yy = hb + r;
            float fy = (float)yy * scale;
            int y0 = min((int)fy, GH - 2);
            float ty = fy - (float)y0;
            _Float16 t1 = (_Float16)ty, t0 = (_Float16)(1.0f - ty);
            h2 w0v = (h2){t0, t0}, w1v = (h2){t1, t1};
            int xi = min(xlo + lx, GW - 1);
            const float4* pa = tsrc + (y0 * GW + xi) * CF4 + q;
            const float4* pb = tsrc + ((y0 + 1) * GW + xi) * CF4 + q;
            float4 A = *pa, B = *pb, R;
            R.x = bcf(bch2(A.x) * w0v + bch2(B.x) * w1v);
            R.y = bcf(bch2(A.y) * w0v + bch2(B.y) * w1v);
            R.z = bcf(bch2(A.z) * w0v + bch2(B.z) * w1v);
            R.w = bcf(bch2(A.w) * w0v + bch2(B.w) * w1v);
            sdst[e] = R;
        }
    } else {
        const float* gnn = grid + (size_t)n * GC * GD * GH * GW;
        for (int e = tid; e < BY * XS * CELLE; e += BX * BY) {
            int r  = e / (XS * CELLE);
            int t  = e - r * (XS * CELLE);
            int lx = t / CELLE, u = t - lx * CELLE;
            int z0 = u / GC, c = u - z0 * GC;
            int yy = hb + r;
            float fy = (float)yy * scale;
            int y0 = min((int)fy, GH - 2);
            float ty = fy - (float)y0;
            int xi = min(xlo + lx, GW - 1);
            const float* gp = gnn + ((c * GD + z0) * GH + y0) * GW + xi;
            float a0 = gp[0],  a1 = gp[256];        // z0 / z0+1 at y0
            float b0 = gp[16], b1 = gp[272];        // z0 / z0+1 at y0+1
            sgrid[e] = pkrtz(fmaf(b0 - a0, ty, a0), fmaf(b1 - a1, ty, a1));
        }
    }
    __syncthreads();

    const int h  = hb + threadIdx.y;
    const int w0 = wb + threadIdx.x * PX;

    // ---- weights to registers ----
    float w1c[3][3];
    #pragma unroll
    for (int o = 0; o < 3; ++o)
        #pragma unroll
        for (int i = 0; i < 3; ++i)
            w1c[o][i] = w1[o * 3 + i];
    const float biasv = bias[0];

    // ---- 3x3 conv over 3 ch for 4 pixels, rows from LDS ----
    v2f a3p[3][2];
    #pragma unroll
    for (int o = 0; o < 3; ++o) {
        float b = b3[o];
        a3p[o][0] = (v2f){b, b};
        a3p[o][1] = (v2f){b, b};
    }
    float rgb[3][PX];

    #pragma unroll
    for (int i = 0; i < 3; ++i) {
        #pragma unroll
        for (int dy = 0; dy < 3; ++dy) {
            // LDS row: x index k ↔ global x = wb-4+k; window w0-1.. ↔ k = tx*4+3
            const float* rowp = &simg[i * IMCH + (threadIdx.y + dy) * IMW
                                      + (threadIdx.x << 2)];
            float  lhalo = rowp[3];                        // w0-1
            float4 a = *(const float4*)(rowp + 4);         // w0 .. w0+3
            float4 b4 = *(const float4*)(rowp + 8);        // w0+4 .. w0+7
            float row[8];
            row[0] = lhalo;
            row[1] = a.x;  row[2] = a.y;  row[3] = a.z;  row[4] = a.w;
            row[5] = b4.x; row[6] = b4.y; row[7] = b4.z;
            if (dy == 1) {
                #pragma unroll
                for (int j = 0; j < PX; ++j) rgb[i][j] = row[1 + j];
            }
            #pragma unroll
            for (int o = 0; o < 3; ++o) {
                const float* kp = w3 + ((o * 3 + i) * 3 + dy) * 3;
                #pragma unroll
                for (int t = 0; t < 3; ++t) {
                    const float kt = kp[t];
                    v2f kv = (v2f){kt, kt};
                    a3p[o][0] = __builtin_elementwise_fma(
                        kv, (v2f){row[t], row[t + 1]}, a3p[o][0]);
                    a3p[o][1] = __builtin_elementwise_fma(
                        kv, (v2f){row[t + 2], row[t + 3]}, a3p[o][1]);
                }
            }
        }
    }

    const int srow = threadIdx.y * XS;       // this thread-row's cell base
    const float4* sg4 = (const float4*)sgrid;

    float4 ov0, ov1, ov2;
    float* ov0p = &ov0.x; float* ov1p = &ov1.x; float* ov2p = &ov2.x;

    #pragma unroll
    for (int j = 0; j < PX; ++j) {
        // guide
        float gacc = 0.0f;
        #pragma unroll
        for (int o = 0; o < 3; ++o) {
            float x1 = fmaf(w1c[o][0], rgb[0][j],
                       fmaf(w1c[o][1], rgb[1][j], w1c[o][2] * rgb[2][j]));
            x1 = (x1 > 0.0f) ? x1 : LEAK * x1;
            float x3 = a3p[o][j >> 1][j & 1];
            x3 = (x3 > 0.0f) ? x3 : LEAK * x3;
            gacc += x1 + x3;
        }
        float g = fmaf(gacc, (1.0f / 3.0f), biasv);
        g = fminf(fmaxf(g, 0.0f), 1.0f);

        // slice coords (y already folded into LDS)
        float fx = (float)(w0 + j) * scale;
        int x0 = (int)fx;
        x0 = min(x0, GW - 2);
        float tx = fx - (float)x0;
        const int lxr = x0 - xlo;      // 0..4

        float fz = g * 11.0f;
        int z0 = (int)fz;
        z0 = min(z0, GD - 2);
        float tz = fz - (float)z0;
        h2 hz = pkrtz(1.0f - tz, tz);
        _Float16 hx0 = (_Float16)(1.0f - tx), hx1 = (_Float16)tx;
        h2 wA = hz * (h2){hx0, hx0};   // v_pk_mul_f16
        h2 wB = hz * (h2){hx1, hx1};

        const float4* pA = sg4 + (srow + lxr) * CF4 + z0 * 3;
        const float4* pB = pA + CF4;
        float4 A0 = pA[0], A1 = pA[1], A2 = pA[2];
        float4 B0 = pB[0], B1 = pB[1], B2 = pB[2];

        float co[12];
        co[0]  = fdot2f(wA, bch2(A0.x), fdot2f(wB, bch2(B0.x), 0.0f));
        co[1]  = fdot2f(wA, bch2(A0.y), fdot2f(wB, bch2(B0.y), 0.0f));
        co[2]  = fdot2f(wA, bch2(A0.z), fdot2f(wB, bch2(B0.z), 0.0f));
        co[3]  = fdot2f(wA, bch2(A0.w), fdot2f(wB, bch2(B0.w), 0.0f));
        co[4]  = fdot2f(wA, bch2(A1.x), fdot2f(wB, bch2(B1.x), 0.0f));
        co[5]  = fdot2f(wA, bch2(A1.y), fdot2f(wB, bch2(B1.y), 0.0f));
        co[6]  = fdot2f(wA, bch2(A1.z), fdot2f(wB, bch2(B1.z), 0.0f));
        co[7]  = fdot2f(wA, bch2(A1.w), fdot2f(wB, bch2(B1.w), 0.0f));
        co[8]  = fdot2f(wA, bch2(A2.x), fdot2f(wB, bch2(B2.x), 0.0f));
        co[9]  = fdot2f(wA, bch2(A2.y), fdot2f(wB, bch2(B2.y), 0.0f));
        co[10] = fdot2f(wA, bch2(A2.z), fdot2f(wB, bch2(B2.z), 0.0f));
        co[11] = fdot2f(wA, bch2(A2.w), fdot2f(wB, bch2(B2.w), 0.0f));

        // apply
        const float r = rgb[0][j], gg = rgb[1][j], b = rgb[2][j];
        ov0p[j] = fmaf(co[0], r, fmaf(co[1],  gg, fmaf(co[2],  b, co[3])));
        ov1p[j] = fmaf(co[4], r, fmaf(co[5],  gg, fmaf(co[6],  b, co[7])));
        ov2p[j] = fmaf(co[8], r, fmaf(co[9],  gg, fmaf(co[10], b, co[11])));
    }

    // ---- coalesced float4 stores ----
    float* ob = out + (size_t)n * 3 * plane + (size_t)h * W + w0;
    *(float4*)(ob)             = ov0;
    *(float4*)(ob + plane)     = ov1;
    *(float4*)(ob + 2 * plane) = ov2;
}

extern "C" void kernel_launch(void* const* d_in, const int* in_sizes, int n_in,
                              void* d_out, int out_size, void* d_ws, size_t ws_size,
                              hipStream_t stream) {
    const float* grid_p = (const float*)d_in[0];
    const float* full_p = (const float*)d_in[1];
    const float* w1_p   = (const float*)d_in[2];
    const float* w3_p   = (const float*)d_in[3];
    const float* b3_p   = (const float*)d_in[4];
    const float* bias_p = (const float*)d_in[5];
    float* out_p = (float*)d_out;

    const size_t tbytes = (size_t)NIMG * 256 * CELLE * sizeof(h2);  // 540,672 B
    h2* table = (d_ws && ws_size >= tbytes) ? (h2*)d_ws : nullptr;

    if (table) {
        hipLaunchKernelGGL(pairgen, dim3(NIMG * NZ), dim3(256), 0, stream,
                           grid_p, table);
    }

    dim3 block(BX, BY, 1);
    dim3 grid_dim(W / TILE_W, H / BY, NIMG);
    hipLaunchKernelGGL(hdrnet_fused, grid_dim, block, 0, stream,
                       grid_p, full_p, w1_p, w3_p, b3_p, bias_p, table, out_p);
}